// Round 8
// baseline (178.704 us; speedup 1.0000x reference)
//
#include <hip/hip_runtime.h>
#include <cstdint>
#include <cstddef>

// Problem constants
#define B_TOK 4096
#define D_DIM 1024
#define E_NUM 8
#define N3    3072   // 3*D
// H=8, hd=128, top-k=2

typedef float f32x4 __attribute__((ext_vector_type(4)));
typedef __bf16 bf16x8 __attribute__((ext_vector_type(8)));
typedef unsigned short us8 __attribute__((ext_vector_type(8)));

// ---------------- helpers ----------------
__device__ __forceinline__ unsigned short f2bf(float f) {  // RNE f32->bf16
  unsigned u = __float_as_uint(f);
  u += 0x7fffu + ((u >> 16) & 1u);
  return (unsigned short)(u >> 16);
}
__device__ __forceinline__ float bf_lo(unsigned u) { return __uint_as_float(u << 16); }
__device__ __forceinline__ float bf_hi(unsigned u) { return __uint_as_float(u & 0xffff0000u); }

// global->LDS direct staging, 16B per lane; LDS dest = wave-uniform base + lane*16
__device__ __forceinline__ void stage16(const unsigned short* g, unsigned short* lds) {
  __builtin_amdgcn_global_load_lds(
      (const __attribute__((address_space(1))) void*)(uintptr_t)(const void*)g,
      (__attribute__((address_space(3))) void*)(uintptr_t)(void*)lds,
      16, 0, 0);
}

// ---------------- 1) fused preprocess (INTERLEAVED block mapping) ----------------
// R7: two prior transpose structures (64x64 f32, 64x128 bf16) both measured
// 68-70 us -> micro-structure is not the constraint. FETCH (68 MB) << logical
// reads (138 MB): reads are majority L3-hits; HBM side is dominated by the
// 69 MB of WRITES, which both variants issued as 128-B runs (64-row tiles).
// This round: 256r x 32c tiles -> write-side LDS transpose, read-out is
// ds_read_b128 + us8 stores where 32 consecutive lanes form one 512-B output
// run (4x write granularity). Read runs drop to 128 B (L3-served, cheap).
// LDS stays 16,896 B ([32][264] u16) so gate residency + interleave unchanged.
// NOTE (R1): routing stays separate (per-block __threadfence = L2 storms).
#define PREP_B   B_TOK             // 4096 gate blocks
#define TQ_B3    (4 * 96 * 8)      // 3072 Wqkv tiles (256r x 32c)
#define TP_B3    (4 * 32)          // 128 Wp tiles
#define TR_B3    (TQ_B3 + TP_B3)   // 3200
#define FUSED_B  (128 * 57)        // 7296 = 128 groups x (32 gate + 25 transpose)

__global__ __launch_bounds__(256)
void fused_prep_kernel(const float* __restrict__ x, const float* __restrict__ y,
                       const float* __restrict__ Wg, const float* __restrict__ bg,
                       const float* __restrict__ ebias,
                       const float* __restrict__ Wqkv, const float* __restrict__ Wp,
                       unsigned short* __restrict__ xb, unsigned short* __restrict__ yb,
                       unsigned short* __restrict__ wqkvT, unsigned short* __restrict__ wpT,
                       int* __restrict__ tok_expert, float* __restrict__ tok_weight)
{
  __shared__ unsigned short tbf[32][264];  // bf16 staging, col-major tile (16,896 B)
  __shared__ float red[4][E_NUM];          // gate reduce
  const int t = threadIdx.x;
  const int grp = blockIdx.x / 57;
  const int pos = blockIdx.x % 57;

  if (pos < 32) {
    // ---- per-token convert + gate ----
    const int b = grp * 32 + pos;
    const int w = t >> 6, l = t & 63;
    float4 xv = *(const float4*)(x + (size_t)b * D_DIM + 4 * t);
    float4 yv = *(const float4*)(y + (size_t)b * D_DIM + 4 * t);
    ushort4 px; px.x = f2bf(xv.x); px.y = f2bf(xv.y); px.z = f2bf(xv.z); px.w = f2bf(xv.w);
    *(ushort4*)(xb + (size_t)b * D_DIM + 4 * t) = px;
    ushort4 py; py.x = f2bf(yv.x); py.y = f2bf(yv.y); py.z = f2bf(yv.z); py.w = f2bf(yv.w);
    *(ushort4*)(yb + (size_t)b * D_DIM + 4 * t) = py;

    float a[E_NUM];
#pragma unroll
    for (int e = 0; e < E_NUM; ++e) a[e] = 0.f;
    const float xa[4] = {xv.x, xv.y, xv.z, xv.w};
#pragma unroll
    for (int j = 0; j < 4; ++j) {
      const float4* wr4 = (const float4*)(Wg + (size_t)(4 * t + j) * E_NUM);
      float4 w0 = wr4[0], w1 = wr4[1];
      a[0] += xa[j] * w0.x; a[1] += xa[j] * w0.y;
      a[2] += xa[j] * w0.z; a[3] += xa[j] * w0.w;
      a[4] += xa[j] * w1.x; a[5] += xa[j] * w1.y;
      a[6] += xa[j] * w1.z; a[7] += xa[j] * w1.w;
    }

    // reduce-scatter butterfly: 10 shuffles instead of 48.
    float s0, s1, s2, s3;
    {
      const bool b0 = (l & 1);
      float r0_ = __shfl_xor(b0 ? a[0] : a[4], 1);
      float r1_ = __shfl_xor(b0 ? a[1] : a[5], 1);
      float r2_ = __shfl_xor(b0 ? a[2] : a[6], 1);
      float r3_ = __shfl_xor(b0 ? a[3] : a[7], 1);
      s0 = (b0 ? a[4] : a[0]) + r0_;
      s1 = (b0 ? a[5] : a[1]) + r1_;
      s2 = (b0 ? a[6] : a[2]) + r2_;
      s3 = (b0 ? a[7] : a[3]) + r3_;
    }
    float u0, u1;
    {
      const bool b1 = (l & 2);
      float r0_ = __shfl_xor(b1 ? s0 : s2, 2);
      float r1_ = __shfl_xor(b1 ? s1 : s3, 2);
      u0 = (b1 ? s2 : s0) + r0_;
      u1 = (b1 ? s3 : s1) + r1_;
    }
    float v_;
    {
      const bool b2 = (l & 4);
      float r0_ = __shfl_xor(b2 ? u0 : u1, 4);
      v_ = (b2 ? u1 : u0) + r0_;
    }
    v_ += __shfl_xor(v_, 8);
    v_ += __shfl_xor(v_, 16);
    v_ += __shfl_xor(v_, 32);
    if (l < 8) {
      const int e = ((l & 1) << 2) | (l & 2) | ((l >> 2) & 1);   // bitrev3
      red[w][e] = v_;
    }
    __syncthreads();
    if (t == 0) {
      float logit[E_NUM];
#pragma unroll
      for (int e = 0; e < E_NUM; ++e)
        logit[e] = red[0][e] + red[1][e] + red[2][e] + red[3][e] + bg[e];
      float m = logit[0];
#pragma unroll
      for (int e = 1; e < E_NUM; ++e) m = fmaxf(m, logit[e]);
      float p[E_NUM], s = 0.f;
#pragma unroll
      for (int e = 0; e < E_NUM; ++e) { p[e] = expf(logit[e] - m); s += p[e]; }
      float inv = 1.f / s;
      float gate[E_NUM];
#pragma unroll
      for (int e = 0; e < E_NUM; ++e) gate[e] = p[e] * inv + ebias[e];
      int i1 = 0; float v1 = gate[0];
#pragma unroll
      for (int e = 1; e < E_NUM; ++e) if (gate[e] > v1) { v1 = gate[e]; i1 = e; }
      int i2 = -1; float v2 = -1e30f;
#pragma unroll
      for (int e = 0; e < E_NUM; ++e) if (e != i1 && gate[e] > v2) { v2 = gate[e]; i2 = e; }
      tok_expert[b * 2] = i1; tok_expert[b * 2 + 1] = i2;
      tok_weight[b * 2] = v1; tok_weight[b * 2 + 1] = v2;
    }
    return;
  }

  // ---- transpose branch: 256 rows x 32 cols, write-side LDS transpose ----
  const int tid2 = grp * 25 + (pos - 32);   // 0..3199
  const float* in; unsigned short* outp; int R, C, r0, c0; size_t mo;
  if (tid2 < TQ_B3) {
    int rt = tid2 & 3; int rest = tid2 >> 2;    // rest 0..767
    int ct = rest % 96; int mz = rest / 96;
    in = Wqkv; outp = wqkvT; R = 1024; C = 3072;
    r0 = rt * 256; c0 = ct * 32; mo = (size_t)mz * R * C;
  } else {
    int id = tid2 - TQ_B3;
    int rt = id & 3; int ct = id >> 2;          // ct 0..31
    in = Wp; outp = wpT; R = 1024; C = 1024;
    r0 = rt * 256; c0 = ct * 32; mo = 0;
  }
  // load: thread t owns global row r0+t (cols c0..c0+31 = 8 float4, 128 B).
  // Reads are 128-B runs per lane — acceptable: majority L3-hit (FETCH ev.).
  // Transpose happens on the LDS WRITE: tbf[c][t] (2 lanes/bank = free).
  {
    const float* src = in + mo + (size_t)(r0 + t) * C + c0;
    float4 v0 = ((const float4*)src)[0];
    float4 v1 = ((const float4*)src)[1];
    float4 v2 = ((const float4*)src)[2];
    float4 v3 = ((const float4*)src)[3];
    float4 v4 = ((const float4*)src)[4];
    float4 v5 = ((const float4*)src)[5];
    float4 v6 = ((const float4*)src)[6];
    float4 v7 = ((const float4*)src)[7];
    const float4 vv[8] = {v0, v1, v2, v3, v4, v5, v6, v7};
#pragma unroll
    for (int q = 0; q < 8; ++q) {
      tbf[4 * q + 0][t] = f2bf(vv[q].x);
      tbf[4 * q + 1][t] = f2bf(vv[q].y);
      tbf[4 * q + 2][t] = f2bf(vv[q].z);
      tbf[4 * q + 3][t] = f2bf(vv[q].w);
    }
  }
  __syncthreads();
  // read-out: thread t, pass p: output row c = (t>>5) + 8p, col base
  // rb = 8*(t&31). ds_read_b128 (contiguous in LDS) + us8 store; lanes
  // (t&31)=0..31 form one contiguous 512-B output run.
  {
    const int rb = 8 * (t & 31);
    const int ch = t >> 5;                 // 0..7
#pragma unroll
    for (int p = 0; p < 4; ++p) {
      const int c = ch + 8 * p;
      us8 o = *(const us8*)&tbf[c][rb];
      *(us8*)(outp + mo + (size_t)(c0 + c) * R + (r0 + rb)) = o;
    }
  }
}

// ---------------- 2) routing: single block, deterministic, no global atomics ----------------
// Serial on the wall-clock critical path -> R5: vectorized loads (int4/float4)
// + expert ids packed 3b x 8/word in registers (static shifts under full
// unroll, rule #20) so Phase C never re-reads tok_expert.
#define NT_ENT (B_TOK * 2)      // 8192
#define ENT_PER_T (NT_ENT / 256)  // 32
__global__ __launch_bounds__(256)
void route_kernel(const int* __restrict__ tok_expert, const float* __restrict__ tok_weight,
                  int* __restrict__ eoff, int* __restrict__ slot_token,
                  float* __restrict__ slot_weight, int* __restrict__ tok_slot)
{
  __shared__ int cnt[256][E_NUM];      // per-thread per-expert, becomes exclusive prefix
  __shared__ int sub[E_NUM][8];        // per-expert subrange sums (8 groups of 32 threads)
  __shared__ int tot[E_NUM];
  __shared__ int eoff_s[E_NUM];
  const int t = threadIdx.x;

  // Phase A: vectorized histogram + register-packed expert ids.
  unsigned pk[4] = {0u, 0u, 0u, 0u};
  {
    int h[E_NUM];
#pragma unroll
    for (int e = 0; e < E_NUM; ++e) h[e] = 0;
#pragma unroll
    for (int q = 0; q < 8; ++q) {                       // 8 x int4 = 32 entries
      int4 v = ((const int4*)tok_expert)[t * 8 + q];
      const int s_ = (q & 1) * 12;
      pk[q >> 1] |= ((unsigned)v.x << s_)       | ((unsigned)v.y << (s_ + 3))
                  | ((unsigned)v.z << (s_ + 6)) | ((unsigned)v.w << (s_ + 9));
      h[v.x]++; h[v.y]++; h[v.z]++; h[v.w]++;
    }
#pragma unroll
    for (int e = 0; e < E_NUM; ++e) cnt[t][e] = h[e];
  }
  __syncthreads();

  // Phase B1: subrange sums + in-subrange exclusive prefix (64 threads: e = t&7, g = t>>3)
  if (t < 64) {
    int e = t & 7, g = t >> 3;
    int run = 0;
    for (int i = g * 32; i < (g + 1) * 32; ++i) {
      int v = cnt[i][e];
      cnt[i][e] = run;
      run += v;
    }
    sub[e][g] = run;
  }
  __syncthreads();
  // Phase B2: scan subrange sums per expert (8 threads)
  if (t < E_NUM) {
    int run = 0;
#pragma unroll
    for (int g = 0; g < 8; ++g) {
      int v = sub[t][g];
      sub[t][g] = run;
      run += v;
    }
    tot[t] = run;
  }
  __syncthreads();
  // Phase B3: apply subrange base
  if (t < 64) {
    int e = t & 7, g = t >> 3;
    int basev = sub[e][g];
    for (int i = g * 32; i < (g + 1) * 32; ++i) cnt[i][e] += basev;
  }
  // Phase B4: expert offsets
  if (t == 0) {
    int a = 0;
#pragma unroll
    for (int e = 0; e < E_NUM; ++e) { eoff_s[e] = a; eoff[e] = a; a += tot[e]; }
    eoff[E_NUM] = a;
  }
  __syncthreads();

  // Phase C: assign slots; ids from registers, weights via float4 (same order
  // as the scalar version -> identical deterministic slot assignment).
#pragma unroll
  for (int q = 0; q < 8; ++q) {
    float4 fv = ((const float4*)tok_weight)[t * 8 + q];
    const float fr[4] = {fv.x, fv.y, fv.z, fv.w};
    const int s_ = (q & 1) * 12;
#pragma unroll
    for (int r = 0; r < 4; ++r) {
      int p = 4 * q + r;
      int i = t * ENT_PER_T + p;
      int e = (int)((pk[q >> 1] >> (s_ + 3 * r)) & 7u);
      int sl = eoff_s[e] + cnt[t][e];
      cnt[t][e] = cnt[t][e] + 1;
      slot_token[sl] = i >> 1;
      slot_weight[sl] = fr[r];
      tok_slot[i] = sl;
    }
  }
}

// ---------------- 4) MoE gathered GEMM ----------------
// 128x128 tile, BK=64, 4 waves (2x2), 16x16x32 MFMA, global_load_lds staging,
// LDS XOR-swizzle (T2) + bijective XCD-chunk swizzle (T1) on a 1-D grid.
// MEASURED BRACKET (R0-R5): this exact config = 68 us. Variants all worse:
// compacted work-list (71, cross-expert L2 thrash), mt-fastest walk (80,
// sprinkled dead blocks starve residency), persistent 1536-block (73),
// counted-vmcnt 2-deep dbuf (90: LDS 64KB halves residency, prefetch window
// breaks L2 A-reuse, FETCH 83->118 MB — m232's 128^2+8ph null reproduced).
// 256^2 8-phase is grid-infeasible (384 blocks @ 1/CU -> 1.5 residency
// rounds). This kernel is at its structural plateau; leave it alone.
#define MOE_NWG 6144            // 24 nt x 32 mt x 8 e
#define MOE_CPX (MOE_NWG / 8)   // 768 blocks per XCD chunk
__global__ __launch_bounds__(256, 4)
void moe_gemm_kernel(const unsigned short* __restrict__ yb, const unsigned short* __restrict__ xb,
                     const unsigned short* __restrict__ wqkvT,   // [E][3072][1024] bf16
                     unsigned short* __restrict__ qkvslot,       // [8192][3072] bf16
                     const int* __restrict__ slot_token, const float* __restrict__ slot_weight,
                     const int* __restrict__ eoff)
{
  __shared__ __align__(16) unsigned short As[128 * 64];
  __shared__ __align__(16) unsigned short Bs[128 * 64];

  // T1: id%8 ~ XCD; give each XCD a contiguous logical chunk (nt fastest within
  // chunk -> consecutive swz share the same (e,mt) A-tile). Live blocks are
  // ids 0..1535 (dispatch first); dead blocks trail and exit pre-barrier.
  const int id = blockIdx.x;
  const int swz = (id & 7) * MOE_CPX + (id >> 3);
  const int nt = swz % 24;
  const int mtE = swz / 24;
  const int mt = mtE & 31;
  const int e  = mtE >> 5;

  const int tid = threadIdx.x;
  const int w = tid >> 6, l = tid & 63;
  const int base = eoff[e], cnt = eoff[e + 1] - base;
  if (mt * 128 >= cnt) return;
  const int slot_base = base + mt * 128;
  const int valid = min(128, cnt - mt * 128);
  const int nc = nt * 128;

  const unsigned short* Abase = (nt < 8) ? yb : xb;
  const unsigned short* Bbase = wqkvT + ((size_t)e * N3 + nc) * D_DIM;

  // staging: lds row r = (w*4+i)*8 + l/8; source chunk = (l&7) ^ (r&7), r&7 == l>>3
  const int csw = (((l & 7) ^ (l >> 3)) << 3);   // swizzled element offset within 64-elem K segment
  const unsigned short* aptr[4];
  const unsigned short* bptr[4];
#pragma unroll
  for (int i = 0; i < 4; ++i) {
    int r = (w * 4 + i) * 8 + (l >> 3);
    int rA = r < valid ? r : (valid - 1);                  // clamp: safe garbage, not stored
    int t = slot_token[slot_base + rA];
    aptr[i] = Abase + (size_t)t * D_DIM + csw;
    bptr[i] = Bbase + (size_t)r * D_DIM + csw;
  }

  f32x4 acc[4][4];
#pragma unroll
  for (int mi = 0; mi < 4; ++mi)
#pragma unroll
    for (int ni = 0; ni < 4; ++ni) acc[mi][ni] = (f32x4){0.f, 0.f, 0.f, 0.f};

  const int wr = w >> 1, wc = w & 1;
  const int arow = wr * 64 + (l & 15);    // arow&7 == l&7
  const int brow = wc * 64 + (l & 15);    // brow&7 == l&7

  for (int kt = 0; kt < 16; ++kt) {
    __syncthreads();   // prev compute done before overwrite
#pragma unroll
    for (int i = 0; i < 4; ++i) {
      stage16(aptr[i] + kt * 64, &As[(w * 4 + i) * 512]);
      stage16(bptr[i] + kt * 64, &Bs[(w * 4 + i) * 512]);
    }
    __syncthreads();   // compiler drains vmcnt before barrier -> tiles resident
#pragma unroll
    for (int ks = 0; ks < 2; ++ks) {
      // pre-swizzle element offset: chunk cc = ks*4 + (l>>4); chunk' = cc ^ (row&7) = cc ^ (l&7)
      const int eoffk = (((ks * 4 + (l >> 4)) ^ (l & 7)) << 3);
      bf16x8 af[4], bfv[4];
#pragma unroll
      for (int mi = 0; mi < 4; ++mi)
        af[mi] = *(const bf16x8*)&As[(arow + mi * 16) * 64 + eoffk];
#pragma unroll
      for (int ni = 0; ni < 4; ++ni)
        bfv[ni] = *(const bf16x8*)&Bs[(brow + ni * 16) * 64 + eoffk];
#pragma unroll
      for (int mi = 0; mi < 4; ++mi)
#pragma unroll
        for (int ni = 0; ni < 4; ++ni)
          acc[mi][ni] = __builtin_amdgcn_mfma_f32_16x16x32_bf16(af[mi], bfv[ni], acc[mi][ni], 0, 0, 0);
    }
  }

  // epilogue: scale by gate weight, store bf16. C/D map: col=lane&15, row=(lane>>4)*4+j
  const int crow0 = wr * 64 + ((l >> 4) << 2);
  const int ccol = wc * 64 + (l & 15);
#pragma unroll
  for (int mi = 0; mi < 4; ++mi) {
#pragma unroll
    for (int j = 0; j < 4; ++j) {
      int rloc = crow0 + mi * 16 + j;
      if (rloc < valid) {
        int sl = slot_base + rloc;
        float wgt = slot_weight[sl];
        size_t ro = (size_t)sl * N3 + nc + ccol;
#pragma unroll
        for (int ni = 0; ni < 4; ++ni)
          qkvslot[ro + ni * 16] = f2bf(acc[mi][ni][j] * wgt);
      }
    }
  }
}

// ---------------- 5) per-token head-attention (8x8), LDS-staged coalesced output ----------------
__global__ __launch_bounds__(256)
void attn_kernel(const unsigned short* __restrict__ qkvslot,
                 const int* __restrict__ tok_slot,
                 unsigned short* __restrict__ attno)
{
  __shared__ unsigned short obuf[4][1024];
  const int w = threadIdx.x >> 6, l = threadIdx.x & 63;
  const int b0 = blockIdx.x * 4;
  const int b = b0 + w;
  const int s0 = tok_slot[b * 2], s1 = tok_slot[b * 2 + 1];
  const unsigned* p0 = (const unsigned*)(qkvslot + (size_t)s0 * N3);
  const unsigned* p1 = (const unsigned*)(qkvslot + (size_t)s1 * N3);

  float q[8][2], k[8][2], v[8][2];
#pragma unroll
  for (int i = 0; i < 8; ++i) {
    unsigned a0 = p0[i * 64 + l],        a1 = p1[i * 64 + l];         // q block
    unsigned b0v = p0[512 + i * 64 + l], b1v = p1[512 + i * 64 + l];  // k block
    unsigned c0 = p0[1024 + i * 64 + l], c1 = p1[1024 + i * 64 + l];  // v block
    q[i][0] = bf_lo(a0) + bf_lo(a1); q[i][1] = bf_hi(a0) + bf_hi(a1);
    k[i][0] = bf_lo(b0v) + bf_lo(b1v); k[i][1] = bf_hi(b0v) + bf_hi(b1v);
    v[i][0] = bf_lo(c0) + bf_lo(c1); v[i][1] = bf_hi(c0) + bf_hi(c1);
  }

  float S[8][8];
#pragma unroll
  for (int i = 0; i < 8; ++i)
#pragma unroll
    for (int j = 0; j < 8; ++j)
      S[i][j] = q[i][0] * k[j][0] + q[i][1] * k[j][1];

#pragma unroll
  for (int off = 32; off; off >>= 1)
#pragma unroll
    for (int i = 0; i < 8; ++i)
#pragma unroll
      for (int j = 0; j < 8; ++j)
        S[i][j] += __shfl_xor(S[i][j], off);

  const float scale = 0.08838834764831843f;  // 128^-0.5
#pragma unroll
  for (int i = 0; i < 8; ++i) {
    float m = S[i][0];
#pragma unroll
    for (int j = 1; j < 8; ++j) m = fmaxf(m, S[i][j]);
    float P[8], sum = 0.f;
#pragma unroll
    for (int j = 0; j < 8; ++j) { P[j] = expf((S[i][j] - m) * scale); sum += P[j]; }
    float inv = 1.f / sum;
    float o0 = 0.f, o1 = 0.f;
#pragma unroll
    for (int j = 0; j < 8; ++j) { o0 += P[j] * v[j][0]; o1 += P[j] * v[j][1]; }
    obuf[w][(2 * l) * 8 + i]     = f2bf(o0 * inv);
    obuf[w][(2 * l + 1) * 8 + i] = f2bf(o1 * inv);
  }
  __syncthreads();
  const int t = threadIdx.x;
#pragma unroll
  for (int p = 0; p < 4; ++p) {
    int j = t + 256 * p;              // ushort4 index among 1024
    int tk = j >> 8, c = j & 255;
    *(ushort4*)(attno + (size_t)(b0 + tk) * D_DIM + 4 * c) = *(ushort4*)&obuf[tk][4 * c];
  }
}

// ---------------- 6) final projection: out = attno @ Wp + bp (fp32 out) ----------------
// 64x128 tiles -> grid 8x64 = 512 blocks = 2/CU so cross-block overlap hides barrier drain.
__global__ __launch_bounds__(256, 4)
void final_gemm_kernel(const unsigned short* __restrict__ attno,
                       const unsigned short* __restrict__ wpT,   // [1024][1024] bf16 (N x K)
                       const float* __restrict__ bp,
                       float* __restrict__ out)
{
  __shared__ __align__(16) unsigned short As[64 * 64];    //  8 KB
  __shared__ __align__(16) unsigned short Bs[128 * 64];   // 16 KB

  const int tid = threadIdx.x;
  const int w = tid >> 6, l = tid & 63;
  const int nt = blockIdx.x, mt = blockIdx.y;

  const int csw = (((l & 7) ^ (l >> 3)) << 3);
  const unsigned short* aptr[2];
  const unsigned short* bptr[4];
#pragma unroll
  for (int i = 0; i < 2; ++i) {
    int r = (w * 2 + i) * 8 + (l >> 3);      // 0..63
    aptr[i] = attno + (size_t)(mt * 64 + r) * D_DIM + csw;
  }
#pragma unroll
  for (int i = 0; i < 4; ++i) {
    int r = (w * 4 + i) * 8 + (l >> 3);      // 0..127
    bptr[i] = wpT + (size_t)(nt * 128 + r) * D_DIM + csw;
  }

  f32x4 acc[2][4];
#pragma unroll
  for (int mi = 0; mi < 2; ++mi)
#pragma unroll
    for (int ni = 0; ni < 4; ++ni) acc[mi][ni] = (f32x4){0.f, 0.f, 0.f, 0.f};

  const int wr = w >> 1, wc = w & 1;
  const int arow = wr * 32 + (l & 15);   // arow&7 == l&7
  const int brow = wc * 64 + (l & 15);

  for (int kt = 0; kt < 16; ++kt) {
    __syncthreads();
#pragma unroll
    for (int i = 0; i < 2; ++i)
      stage16(aptr[i] + kt * 64, &As[(w * 2 + i) * 512]);
#pragma unroll
    for (int i = 0; i < 4; ++i)
      stage16(bptr[i] + kt * 64, &Bs[(w * 4 + i) * 512]);
    __syncthreads();
#pragma unroll
    for (int ks = 0; ks < 2; ++ks) {
      const int eoffk = (((ks * 4 + (l >> 4)) ^ (l & 7)) << 3);
      bf16x8 af[2], bfv[4];
#pragma unroll
      for (int mi = 0; mi < 2; ++mi)
        af[mi] = *(const bf16x8*)&As[(arow + mi * 16) * 64 + eoffk];
#pragma unroll
      for (int ni = 0; ni < 4; ++ni)
        bfv[ni] = *(const bf16x8*)&Bs[(brow + ni * 16) * 64 + eoffk];
#pragma unroll
      for (int mi = 0; mi < 2; ++mi)
#pragma unroll
        for (int ni = 0; ni < 4; ++ni)
          acc[mi][ni] = __builtin_amdgcn_mfma_f32_16x16x32_bf16(af[mi], bfv[ni], acc[mi][ni], 0, 0, 0);
    }
  }

  const int crow0 = wr * 32 + ((l >> 4) << 2);
  const int ccol = wc * 64 + (l & 15);
#pragma unroll
  for (int mi = 0; mi < 2; ++mi) {
#pragma unroll
    for (int j = 0; j < 4; ++j) {
      int rg = mt * 64 + crow0 + mi * 16 + j;
#pragma unroll
      for (int ni = 0; ni < 4; ++ni) {
        int cg = nt * 128 + ccol + ni * 16;
        out[(size_t)rg * D_DIM + cg] = acc[mi][ni][j] + bp[cg];
      }
    }
  }
}

// ---------------- host launcher ----------------
extern "C" void kernel_launch(void* const* d_in, const int* in_sizes, int n_in,
                              void* d_out, int out_size, void* d_ws, size_t ws_size,
                              hipStream_t stream)
{
  const float* x     = (const float*)d_in[0];
  const float* y     = (const float*)d_in[1];
  const float* Wqkv  = (const float*)d_in[2];
  const float* Wg    = (const float*)d_in[3];
  const float* bg    = (const float*)d_in[4];
  const float* Wp    = (const float*)d_in[5];
  const float* bp    = (const float*)d_in[6];
  const float* ebias = (const float*)d_in[7];
  float* out = (float*)d_out;

  char* ws = (char*)d_ws;
  size_t off_b = 0;
  auto take = [&](size_t bytes) -> char* {
    char* p = ws + off_b;
    off_b += (bytes + 255) & ~(size_t)255;
    return p;
  };
  unsigned short* xb       = (unsigned short*)take((size_t)B_TOK * D_DIM * 2);          //  8.4 MB
  unsigned short* yb       = (unsigned short*)take((size_t)B_TOK * D_DIM * 2);          //  8.4 MB
  unsigned short* wqkvT    = (unsigned short*)take((size_t)E_NUM * N3 * D_DIM * 2);     // 50.3 MB
  unsigned short* wpT      = (unsigned short*)take((size_t)D_DIM * D_DIM * 2);          //  2.1 MB
  unsigned short* qkvslot  = (unsigned short*)take((size_t)B_TOK * 2 * N3 * 2);         // 50.3 MB
  unsigned short* attno    = (unsigned short*)take((size_t)B_TOK * D_DIM * 2);          //  8.4 MB
  int*   eoff        = (int*)take(16 * 4);
  int*   tok_expert  = (int*)take((size_t)B_TOK * 2 * 4);
  float* tok_weight  = (float*)take((size_t)B_TOK * 2 * 4);
  int*   tok_slot    = (int*)take((size_t)B_TOK * 2 * 4);
  int*   slot_token  = (int*)take((size_t)B_TOK * 2 * 4);
  float* slot_weight = (float*)take((size_t)B_TOK * 2 * 4);

  if (ws_size < off_b) return;  // ~128.5 MB required

  fused_prep_kernel<<<FUSED_B, 256, 0, stream>>>(x, y, Wg, bg, ebias, Wqkv, Wp,
                                                 xb, yb, wqkvT, wpT, tok_expert, tok_weight);
  route_kernel<<<1, 256, 0, stream>>>(tok_expert, tok_weight, eoff, slot_token,
                                      slot_weight, tok_slot);
  moe_gemm_kernel<<<MOE_NWG, 256, 0, stream>>>(yb, xb, wqkvT, qkvslot,
                                               slot_token, slot_weight, eoff);
  attn_kernel<<<B_TOK / 4, 256, 0, stream>>>(qkvslot, tok_slot, attno);
  final_gemm_kernel<<<dim3(8, 64), 256, 0, stream>>>(attno, wpT, bp, out);
}

// Round 9
// 159.839 us; speedup vs baseline: 1.1180x; 1.1180x over previous
//
#include <hip/hip_runtime.h>
#include <cstdint>
#include <cstddef>

// Problem constants
#define B_TOK 4096
#define D_DIM 1024
#define E_NUM 8
#define N3    3072   // 3*D
// H=8, hd=128, top-k=2

typedef float f32x4 __attribute__((ext_vector_type(4)));
typedef __bf16 bf16x8 __attribute__((ext_vector_type(8)));

// ---------------- helpers ----------------
__device__ __forceinline__ unsigned short f2bf(float f) {  // RNE f32->bf16
  unsigned u = __float_as_uint(f);
  u += 0x7fffu + ((u >> 16) & 1u);
  return (unsigned short)(u >> 16);
}
__device__ __forceinline__ float bf_lo(unsigned u) { return __uint_as_float(u << 16); }
__device__ __forceinline__ float bf_hi(unsigned u) { return __uint_as_float(u & 0xffff0000u); }

// global->LDS direct staging, 16B per lane; LDS dest = wave-uniform base + lane*16
__device__ __forceinline__ void stage16(const unsigned short* g, unsigned short* lds) {
  __builtin_amdgcn_global_load_lds(
      (const __attribute__((address_space(1))) void*)(uintptr_t)(const void*)g,
      (__attribute__((address_space(3))) void*)(uintptr_t)(void*)lds,
      16, 0, 0);
}

// ---------------- 1) fused preprocess (INTERLEAVED block mapping) ----------------
// 10496 blocks = 256 groups x 41 (16 prep + 25 transpose) so latency-bound gate
// waves co-reside with BW-bound transpose waves on every CU (regime overlap).
// MEASURED BRACKET (R6-R8): this 64x64 f32 structure = 68 us; 64x128 bf16-LDS
// = 70 us; 256x32 write-side transpose = 79 us (wave-uncoalesced reads).
// This is the optimum of three structurally distinct variants — keep it.
// NOTE (R1 post-mortem): fusing the routing tail here with per-block
// __threadfence() release cost ~145 us — 4096 agent-scope fences force L2
// writeback/invalidate storms on non-coherent per-XCD L2s. Routing stays a
// separate kernel; the kernel boundary is the single device-scope flush.
#define PREP_B   B_TOK             // 4096
#define TQ_B     (16 * 48 * 8)     // 6144
#define TP_B     (16 * 16)         // 256
#define FUSED_B  (PREP_B + TQ_B + TP_B)   // 10496 = 41*256

__global__ __launch_bounds__(256)
void fused_prep_kernel(const float* __restrict__ x, const float* __restrict__ y,
                       const float* __restrict__ Wg, const float* __restrict__ bg,
                       const float* __restrict__ ebias,
                       const float* __restrict__ Wqkv, const float* __restrict__ Wp,
                       unsigned short* __restrict__ xb, unsigned short* __restrict__ yb,
                       unsigned short* __restrict__ wqkvT, unsigned short* __restrict__ wpT,
                       int* __restrict__ tok_expert, float* __restrict__ tok_weight)
{
  __shared__ float tile[64][65];     // transpose staging (16.6 KB)
  __shared__ float red[4][E_NUM];    // gate reduce
  const int t = threadIdx.x;
  const int grp = blockIdx.x / 41;
  const int pos = blockIdx.x % 41;

  if (pos < 16) {
    // ---- per-token convert + gate ----
    const int b = grp * 16 + pos;
    const int w = t >> 6, l = t & 63;
    float4 xv = *(const float4*)(x + (size_t)b * D_DIM + 4 * t);
    float4 yv = *(const float4*)(y + (size_t)b * D_DIM + 4 * t);
    ushort4 px; px.x = f2bf(xv.x); px.y = f2bf(xv.y); px.z = f2bf(xv.z); px.w = f2bf(xv.w);
    *(ushort4*)(xb + (size_t)b * D_DIM + 4 * t) = px;
    ushort4 py; py.x = f2bf(yv.x); py.y = f2bf(yv.y); py.z = f2bf(yv.z); py.w = f2bf(yv.w);
    *(ushort4*)(yb + (size_t)b * D_DIM + 4 * t) = py;

    float a[E_NUM];
#pragma unroll
    for (int e = 0; e < E_NUM; ++e) a[e] = 0.f;
    const float xa[4] = {xv.x, xv.y, xv.z, xv.w};
#pragma unroll
    for (int j = 0; j < 4; ++j) {
      const float4* wr4 = (const float4*)(Wg + (size_t)(4 * t + j) * E_NUM);
      float4 w0 = wr4[0], w1 = wr4[1];
      a[0] += xa[j] * w0.x; a[1] += xa[j] * w0.y;
      a[2] += xa[j] * w0.z; a[3] += xa[j] * w0.w;
      a[4] += xa[j] * w1.x; a[5] += xa[j] * w1.y;
      a[6] += xa[j] * w1.z; a[7] += xa[j] * w1.w;
    }

    // reduce-scatter butterfly: 10 shuffles instead of 48.
    // After 3 in-group levels lane l holds the 8-lane-group sum for expert
    // e(l) = bitrev3(l&7); 3 more xor levels -> full-wave sum.
    float s0, s1, s2, s3;
    {
      const bool b0 = (l & 1);
      float r0_ = __shfl_xor(b0 ? a[0] : a[4], 1);
      float r1_ = __shfl_xor(b0 ? a[1] : a[5], 1);
      float r2_ = __shfl_xor(b0 ? a[2] : a[6], 1);
      float r3_ = __shfl_xor(b0 ? a[3] : a[7], 1);
      s0 = (b0 ? a[4] : a[0]) + r0_;
      s1 = (b0 ? a[5] : a[1]) + r1_;
      s2 = (b0 ? a[6] : a[2]) + r2_;
      s3 = (b0 ? a[7] : a[3]) + r3_;
    }
    float u0, u1;
    {
      const bool b1 = (l & 2);
      float r0_ = __shfl_xor(b1 ? s0 : s2, 2);
      float r1_ = __shfl_xor(b1 ? s1 : s3, 2);
      u0 = (b1 ? s2 : s0) + r0_;
      u1 = (b1 ? s3 : s1) + r1_;
    }
    float v_;
    {
      const bool b2 = (l & 4);
      float r0_ = __shfl_xor(b2 ? u0 : u1, 4);
      v_ = (b2 ? u1 : u0) + r0_;
    }
    v_ += __shfl_xor(v_, 8);
    v_ += __shfl_xor(v_, 16);
    v_ += __shfl_xor(v_, 32);
    if (l < 8) {
      const int e = ((l & 1) << 2) | (l & 2) | ((l >> 2) & 1);   // bitrev3
      red[w][e] = v_;
    }
    __syncthreads();
    if (t == 0) {
      float logit[E_NUM];
#pragma unroll
      for (int e = 0; e < E_NUM; ++e)
        logit[e] = red[0][e] + red[1][e] + red[2][e] + red[3][e] + bg[e];
      float m = logit[0];
#pragma unroll
      for (int e = 1; e < E_NUM; ++e) m = fmaxf(m, logit[e]);
      float p[E_NUM], s = 0.f;
#pragma unroll
      for (int e = 0; e < E_NUM; ++e) { p[e] = expf(logit[e] - m); s += p[e]; }
      float inv = 1.f / s;
      float gate[E_NUM];
#pragma unroll
      for (int e = 0; e < E_NUM; ++e) gate[e] = p[e] * inv + ebias[e];
      int i1 = 0; float v1 = gate[0];
#pragma unroll
      for (int e = 1; e < E_NUM; ++e) if (gate[e] > v1) { v1 = gate[e]; i1 = e; }
      int i2 = -1; float v2 = -1e30f;
#pragma unroll
      for (int e = 0; e < E_NUM; ++e) if (e != i1 && gate[e] > v2) { v2 = gate[e]; i2 = e; }
      tok_expert[b * 2] = i1; tok_expert[b * 2 + 1] = i2;
      tok_weight[b * 2] = v1; tok_weight[b * 2 + 1] = v2;
    }
    return;
  }

  // ---- transpose branch: manual 4-deep load ILP ----
  const int tid2 = grp * 25 + (pos - 16);   // 0..6399
  const float* in; unsigned short* outp; int R, C, r0, c0; size_t mo;
  if (tid2 < TQ_B) {
    int id = tid2;
    int rt = id & 15; int rest = id >> 4;
    int ct = rest % 48; int mz = rest / 48;
    in = Wqkv; outp = wqkvT; R = 1024; C = 3072;
    r0 = rt * 64; c0 = ct * 64; mo = (size_t)mz * R * C;
  } else {
    int id = tid2 - TQ_B;
    int rt = id & 15; int ct = id >> 4;
    in = Wp; outp = wpT; R = 1024; C = 1024;
    r0 = rt * 64; c0 = ct * 64; mo = 0;
  }
  const int tq = t & 15;        // 16 float4 columns
  const int tr = t >> 4;        // 16 rows per pass
  {
    const float* src = in + mo + (size_t)(r0 + tr) * C + (c0 + 4 * tq);
    float4 v0 = *(const float4*)(src);
    float4 v1 = *(const float4*)(src + (size_t)16 * C);
    float4 v2 = *(const float4*)(src + (size_t)32 * C);
    float4 v3 = *(const float4*)(src + (size_t)48 * C);
    tile[tr][4 * tq] = v0.x;      tile[tr][4 * tq + 1] = v0.y;
    tile[tr][4 * tq + 2] = v0.z;  tile[tr][4 * tq + 3] = v0.w;
    tile[tr + 16][4 * tq] = v1.x;     tile[tr + 16][4 * tq + 1] = v1.y;
    tile[tr + 16][4 * tq + 2] = v1.z; tile[tr + 16][4 * tq + 3] = v1.w;
    tile[tr + 32][4 * tq] = v2.x;     tile[tr + 32][4 * tq + 1] = v2.y;
    tile[tr + 32][4 * tq + 2] = v2.z; tile[tr + 32][4 * tq + 3] = v2.w;
    tile[tr + 48][4 * tq] = v3.x;     tile[tr + 48][4 * tq + 1] = v3.y;
    tile[tr + 48][4 * tq + 2] = v3.z; tile[tr + 48][4 * tq + 3] = v3.w;
  }
  __syncthreads();
  {
    const int rw = 4 * tq;
#pragma unroll
    for (int p = 0; p < 4; ++p) {
      const int c = tr + 16 * p;
      float a0 = tile[rw][c], a1 = tile[rw + 1][c];
      float a2 = tile[rw + 2][c], a3 = tile[rw + 3][c];
      ushort4 o;
      o.x = f2bf(a0); o.y = f2bf(a1); o.z = f2bf(a2); o.w = f2bf(a3);
      *(ushort4*)(outp + mo + (size_t)(c0 + c) * R + (r0 + rw)) = o;
    }
  }
}

// ---------------- 2) routing: single block, deterministic, no global atomics ----------------
// Serial on the wall-clock critical path -> R5: vectorized loads (int4/float4)
// + expert ids packed 3b x 8/word in registers (static shifts under full
// unroll, rule #20) so Phase C never re-reads tok_expert.
#define NT_ENT (B_TOK * 2)      // 8192
#define ENT_PER_T (NT_ENT / 256)  // 32
__global__ __launch_bounds__(256)
void route_kernel(const int* __restrict__ tok_expert, const float* __restrict__ tok_weight,
                  int* __restrict__ eoff, int* __restrict__ slot_token,
                  float* __restrict__ slot_weight, int* __restrict__ tok_slot)
{
  __shared__ int cnt[256][E_NUM];      // per-thread per-expert, becomes exclusive prefix
  __shared__ int sub[E_NUM][8];        // per-expert subrange sums (8 groups of 32 threads)
  __shared__ int tot[E_NUM];
  __shared__ int eoff_s[E_NUM];
  const int t = threadIdx.x;

  // Phase A: vectorized histogram + register-packed expert ids.
  unsigned pk[4] = {0u, 0u, 0u, 0u};
  {
    int h[E_NUM];
#pragma unroll
    for (int e = 0; e < E_NUM; ++e) h[e] = 0;
#pragma unroll
    for (int q = 0; q < 8; ++q) {                       // 8 x int4 = 32 entries
      int4 v = ((const int4*)tok_expert)[t * 8 + q];
      const int s_ = (q & 1) * 12;
      pk[q >> 1] |= ((unsigned)v.x << s_)       | ((unsigned)v.y << (s_ + 3))
                  | ((unsigned)v.z << (s_ + 6)) | ((unsigned)v.w << (s_ + 9));
      h[v.x]++; h[v.y]++; h[v.z]++; h[v.w]++;
    }
#pragma unroll
    for (int e = 0; e < E_NUM; ++e) cnt[t][e] = h[e];
  }
  __syncthreads();

  // Phase B1: subrange sums + in-subrange exclusive prefix (64 threads: e = t&7, g = t>>3)
  if (t < 64) {
    int e = t & 7, g = t >> 3;
    int run = 0;
    for (int i = g * 32; i < (g + 1) * 32; ++i) {
      int v = cnt[i][e];
      cnt[i][e] = run;
      run += v;
    }
    sub[e][g] = run;
  }
  __syncthreads();
  // Phase B2: scan subrange sums per expert (8 threads)
  if (t < E_NUM) {
    int run = 0;
#pragma unroll
    for (int g = 0; g < 8; ++g) {
      int v = sub[t][g];
      sub[t][g] = run;
      run += v;
    }
    tot[t] = run;
  }
  __syncthreads();
  // Phase B3: apply subrange base
  if (t < 64) {
    int e = t & 7, g = t >> 3;
    int basev = sub[e][g];
    for (int i = g * 32; i < (g + 1) * 32; ++i) cnt[i][e] += basev;
  }
  // Phase B4: expert offsets
  if (t == 0) {
    int a = 0;
#pragma unroll
    for (int e = 0; e < E_NUM; ++e) { eoff_s[e] = a; eoff[e] = a; a += tot[e]; }
    eoff[E_NUM] = a;
  }
  __syncthreads();

  // Phase C: assign slots; ids from registers, weights via float4 (same order
  // as the scalar version -> identical deterministic slot assignment).
#pragma unroll
  for (int q = 0; q < 8; ++q) {
    float4 fv = ((const float4*)tok_weight)[t * 8 + q];
    const float fr[4] = {fv.x, fv.y, fv.z, fv.w};
    const int s_ = (q & 1) * 12;
#pragma unroll
    for (int r = 0; r < 4; ++r) {
      int p = 4 * q + r;
      int i = t * ENT_PER_T + p;
      int e = (int)((pk[q >> 1] >> (s_ + 3 * r)) & 7u);
      int sl = eoff_s[e] + cnt[t][e];
      cnt[t][e] = cnt[t][e] + 1;
      slot_token[sl] = i >> 1;
      slot_weight[sl] = fr[r];
      tok_slot[i] = sl;
    }
  }
}

// ---------------- 4) MoE gathered GEMM ----------------
// 128x128 tile, BK=64, 4 waves (2x2), 16x16x32 MFMA, global_load_lds staging,
// LDS XOR-swizzle (T2) + bijective XCD-chunk swizzle (T1) on a 1-D grid.
// MEASURED BRACKET (R0-R5): this exact config = 68 us. Variants all worse:
// compacted work-list (71, cross-expert L2 thrash), mt-fastest walk (80,
// sprinkled dead blocks starve residency), persistent 1536-block (73),
// counted-vmcnt 2-deep dbuf (90: LDS 64KB halves residency, prefetch window
// breaks L2 A-reuse, FETCH 83->118 MB — m232's 128^2+8ph null reproduced).
// 256^2 8-phase is grid-infeasible (384 blocks @ 1/CU -> 1.5 residency
// rounds). This kernel is at its structural plateau; leave it alone.
#define MOE_NWG 6144            // 24 nt x 32 mt x 8 e
#define MOE_CPX (MOE_NWG / 8)   // 768 blocks per XCD chunk
__global__ __launch_bounds__(256, 4)
void moe_gemm_kernel(const unsigned short* __restrict__ yb, const unsigned short* __restrict__ xb,
                     const unsigned short* __restrict__ wqkvT,   // [E][3072][1024] bf16
                     unsigned short* __restrict__ qkvslot,       // [8192][3072] bf16
                     const int* __restrict__ slot_token, const float* __restrict__ slot_weight,
                     const int* __restrict__ eoff)
{
  __shared__ __align__(16) unsigned short As[128 * 64];
  __shared__ __align__(16) unsigned short Bs[128 * 64];

  // T1: id%8 ~ XCD; give each XCD a contiguous logical chunk (nt fastest within
  // chunk -> consecutive swz share the same (e,mt) A-tile). Live blocks are
  // ids 0..1535 (dispatch first); dead blocks trail and exit pre-barrier.
  const int id = blockIdx.x;
  const int swz = (id & 7) * MOE_CPX + (id >> 3);
  const int nt = swz % 24;
  const int mtE = swz / 24;
  const int mt = mtE & 31;
  const int e  = mtE >> 5;

  const int tid = threadIdx.x;
  const int w = tid >> 6, l = tid & 63;
  const int base = eoff[e], cnt = eoff[e + 1] - base;
  if (mt * 128 >= cnt) return;
  const int slot_base = base + mt * 128;
  const int valid = min(128, cnt - mt * 128);
  const int nc = nt * 128;

  const unsigned short* Abase = (nt < 8) ? yb : xb;
  const unsigned short* Bbase = wqkvT + ((size_t)e * N3 + nc) * D_DIM;

  // staging: lds row r = (w*4+i)*8 + l/8; source chunk = (l&7) ^ (r&7), r&7 == l>>3
  const int csw = (((l & 7) ^ (l >> 3)) << 3);   // swizzled element offset within 64-elem K segment
  const unsigned short* aptr[4];
  const unsigned short* bptr[4];
#pragma unroll
  for (int i = 0; i < 4; ++i) {
    int r = (w * 4 + i) * 8 + (l >> 3);
    int rA = r < valid ? r : (valid - 1);                  // clamp: safe garbage, not stored
    int t = slot_token[slot_base + rA];
    aptr[i] = Abase + (size_t)t * D_DIM + csw;
    bptr[i] = Bbase + (size_t)r * D_DIM + csw;
  }

  f32x4 acc[4][4];
#pragma unroll
  for (int mi = 0; mi < 4; ++mi)
#pragma unroll
    for (int ni = 0; ni < 4; ++ni) acc[mi][ni] = (f32x4){0.f, 0.f, 0.f, 0.f};

  const int wr = w >> 1, wc = w & 1;
  const int arow = wr * 64 + (l & 15);    // arow&7 == l&7
  const int brow = wc * 64 + (l & 15);    // brow&7 == l&7

  for (int kt = 0; kt < 16; ++kt) {
    __syncthreads();   // prev compute done before overwrite
#pragma unroll
    for (int i = 0; i < 4; ++i) {
      stage16(aptr[i] + kt * 64, &As[(w * 4 + i) * 512]);
      stage16(bptr[i] + kt * 64, &Bs[(w * 4 + i) * 512]);
    }
    __syncthreads();   // compiler drains vmcnt before barrier -> tiles resident
#pragma unroll
    for (int ks = 0; ks < 2; ++ks) {
      // pre-swizzle element offset: chunk cc = ks*4 + (l>>4); chunk' = cc ^ (row&7) = cc ^ (l&7)
      const int eoffk = (((ks * 4 + (l >> 4)) ^ (l & 7)) << 3);
      bf16x8 af[4], bfv[4];
#pragma unroll
      for (int mi = 0; mi < 4; ++mi)
        af[mi] = *(const bf16x8*)&As[(arow + mi * 16) * 64 + eoffk];
#pragma unroll
      for (int ni = 0; ni < 4; ++ni)
        bfv[ni] = *(const bf16x8*)&Bs[(brow + ni * 16) * 64 + eoffk];
#pragma unroll
      for (int mi = 0; mi < 4; ++mi)
#pragma unroll
        for (int ni = 0; ni < 4; ++ni)
          acc[mi][ni] = __builtin_amdgcn_mfma_f32_16x16x32_bf16(af[mi], bfv[ni], acc[mi][ni], 0, 0, 0);
    }
  }

  // epilogue: scale by gate weight, store bf16. C/D map: col=lane&15, row=(lane>>4)*4+j
  const int crow0 = wr * 64 + ((l >> 4) << 2);
  const int ccol = wc * 64 + (l & 15);
#pragma unroll
  for (int mi = 0; mi < 4; ++mi) {
#pragma unroll
    for (int j = 0; j < 4; ++j) {
      int rloc = crow0 + mi * 16 + j;
      if (rloc < valid) {
        int sl = slot_base + rloc;
        float wgt = slot_weight[sl];
        size_t ro = (size_t)sl * N3 + nc + ccol;
#pragma unroll
        for (int ni = 0; ni < 4; ++ni)
          qkvslot[ro + ni * 16] = f2bf(acc[mi][ni][j] * wgt);
      }
    }
  }
}

// ---------------- 5) per-token head-attention (8x8), LDS-staged coalesced output ----------------
__global__ __launch_bounds__(256)
void attn_kernel(const unsigned short* __restrict__ qkvslot,
                 const int* __restrict__ tok_slot,
                 unsigned short* __restrict__ attno)
{
  __shared__ unsigned short obuf[4][1024];
  const int w = threadIdx.x >> 6, l = threadIdx.x & 63;
  const int b0 = blockIdx.x * 4;
  const int b = b0 + w;
  const int s0 = tok_slot[b * 2], s1 = tok_slot[b * 2 + 1];
  const unsigned* p0 = (const unsigned*)(qkvslot + (size_t)s0 * N3);
  const unsigned* p1 = (const unsigned*)(qkvslot + (size_t)s1 * N3);

  float q[8][2], k[8][2], v[8][2];
#pragma unroll
  for (int i = 0; i < 8; ++i) {
    unsigned a0 = p0[i * 64 + l],        a1 = p1[i * 64 + l];         // q block
    unsigned b0v = p0[512 + i * 64 + l], b1v = p1[512 + i * 64 + l];  // k block
    unsigned c0 = p0[1024 + i * 64 + l], c1 = p1[1024 + i * 64 + l];  // v block
    q[i][0] = bf_lo(a0) + bf_lo(a1); q[i][1] = bf_hi(a0) + bf_hi(a1);
    k[i][0] = bf_lo(b0v) + bf_lo(b1v); k[i][1] = bf_hi(b0v) + bf_hi(b1v);
    v[i][0] = bf_lo(c0) + bf_lo(c1); v[i][1] = bf_hi(c0) + bf_hi(c1);
  }

  float S[8][8];
#pragma unroll
  for (int i = 0; i < 8; ++i)
#pragma unroll
    for (int j = 0; j < 8; ++j)
      S[i][j] = q[i][0] * k[j][0] + q[i][1] * k[j][1];

#pragma unroll
  for (int off = 32; off; off >>= 1)
#pragma unroll
    for (int i = 0; i < 8; ++i)
#pragma unroll
      for (int j = 0; j < 8; ++j)
        S[i][j] += __shfl_xor(S[i][j], off);

  const float scale = 0.08838834764831843f;  // 128^-0.5
#pragma unroll
  for (int i = 0; i < 8; ++i) {
    float m = S[i][0];
#pragma unroll
    for (int j = 1; j < 8; ++j) m = fmaxf(m, S[i][j]);
    float P[8], sum = 0.f;
#pragma unroll
    for (int j = 0; j < 8; ++j) { P[j] = expf((S[i][j] - m) * scale); sum += P[j]; }
    float inv = 1.f / sum;
    float o0 = 0.f, o1 = 0.f;
#pragma unroll
    for (int j = 0; j < 8; ++j) { o0 += P[j] * v[j][0]; o1 += P[j] * v[j][1]; }
    obuf[w][(2 * l) * 8 + i]     = f2bf(o0 * inv);
    obuf[w][(2 * l + 1) * 8 + i] = f2bf(o1 * inv);
  }
  __syncthreads();
  const int t = threadIdx.x;
#pragma unroll
  for (int p = 0; p < 4; ++p) {
    int j = t + 256 * p;              // ushort4 index among 1024
    int tk = j >> 8, c = j & 255;
    *(ushort4*)(attno + (size_t)(b0 + tk) * D_DIM + 4 * c) = *(ushort4*)&obuf[tk][4 * c];
  }
}

// ---------------- 6) final projection: out = attno @ Wp + bp (fp32 out) ----------------
// 64x128 tiles -> grid 8x64 = 512 blocks = 2/CU so cross-block overlap hides barrier drain.
__global__ __launch_bounds__(256, 4)
void final_gemm_kernel(const unsigned short* __restrict__ attno,
                       const unsigned short* __restrict__ wpT,   // [1024][1024] bf16 (N x K)
                       const float* __restrict__ bp,
                       float* __restrict__ out)
{
  __shared__ __align__(16) unsigned short As[64 * 64];    //  8 KB
  __shared__ __align__(16) unsigned short Bs[128 * 64];   // 16 KB

  const int tid = threadIdx.x;
  const int w = tid >> 6, l = tid & 63;
  const int nt = blockIdx.x, mt = blockIdx.y;

  const int csw = (((l & 7) ^ (l >> 3)) << 3);
  const unsigned short* aptr[2];
  const unsigned short* bptr[4];
#pragma unroll
  for (int i = 0; i < 2; ++i) {
    int r = (w * 2 + i) * 8 + (l >> 3);      // 0..63
    aptr[i] = attno + (size_t)(mt * 64 + r) * D_DIM + csw;
  }
#pragma unroll
  for (int i = 0; i < 4; ++i) {
    int r = (w * 4 + i) * 8 + (l >> 3);      // 0..127
    bptr[i] = wpT + (size_t)(nt * 128 + r) * D_DIM + csw;
  }

  f32x4 acc[2][4];
#pragma unroll
  for (int mi = 0; mi < 2; ++mi)
#pragma unroll
    for (int ni = 0; ni < 4; ++ni) acc[mi][ni] = (f32x4){0.f, 0.f, 0.f, 0.f};

  const int wr = w >> 1, wc = w & 1;
  const int arow = wr * 32 + (l & 15);   // arow&7 == l&7
  const int brow = wc * 64 + (l & 15);

  for (int kt = 0; kt < 16; ++kt) {
    __syncthreads();
#pragma unroll
    for (int i = 0; i < 2; ++i)
      stage16(aptr[i] + kt * 64, &As[(w * 2 + i) * 512]);
#pragma unroll
    for (int i = 0; i < 4; ++i)
      stage16(bptr[i] + kt * 64, &Bs[(w * 4 + i) * 512]);
    __syncthreads();
#pragma unroll
    for (int ks = 0; ks < 2; ++ks) {
      const int eoffk = (((ks * 4 + (l >> 4)) ^ (l & 7)) << 3);
      bf16x8 af[2], bfv[4];
#pragma unroll
      for (int mi = 0; mi < 2; ++mi)
        af[mi] = *(const bf16x8*)&As[(arow + mi * 16) * 64 + eoffk];
#pragma unroll
      for (int ni = 0; ni < 4; ++ni)
        bfv[ni] = *(const bf16x8*)&Bs[(brow + ni * 16) * 64 + eoffk];
#pragma unroll
      for (int mi = 0; mi < 2; ++mi)
#pragma unroll
        for (int ni = 0; ni < 4; ++ni)
          acc[mi][ni] = __builtin_amdgcn_mfma_f32_16x16x32_bf16(af[mi], bfv[ni], acc[mi][ni], 0, 0, 0);
    }
  }

  const int crow0 = wr * 32 + ((l >> 4) << 2);
  const int ccol = wc * 64 + (l & 15);
#pragma unroll
  for (int mi = 0; mi < 2; ++mi) {
#pragma unroll
    for (int j = 0; j < 4; ++j) {
      int rg = mt * 64 + crow0 + mi * 16 + j;
#pragma unroll
      for (int ni = 0; ni < 4; ++ni) {
        int cg = nt * 128 + ccol + ni * 16;
        out[(size_t)rg * D_DIM + cg] = acc[mi][ni][j] + bp[cg];
      }
    }
  }
}

// ---------------- host launcher ----------------
extern "C" void kernel_launch(void* const* d_in, const int* in_sizes, int n_in,
                              void* d_out, int out_size, void* d_ws, size_t ws_size,
                              hipStream_t stream)
{
  const float* x     = (const float*)d_in[0];
  const float* y     = (const float*)d_in[1];
  const float* Wqkv  = (const float*)d_in[2];
  const float* Wg    = (const float*)d_in[3];
  const float* bg    = (const float*)d_in[4];
  const float* Wp    = (const float*)d_in[5];
  const float* bp    = (const float*)d_in[6];
  const float* ebias = (const float*)d_in[7];
  float* out = (float*)d_out;

  char* ws = (char*)d_ws;
  size_t off_b = 0;
  auto take = [&](size_t bytes) -> char* {
    char* p = ws + off_b;
    off_b += (bytes + 255) & ~(size_t)255;
    return p;
  };
  unsigned short* xb       = (unsigned short*)take((size_t)B_TOK * D_DIM * 2);          //  8.4 MB
  unsigned short* yb       = (unsigned short*)take((size_t)B_TOK * D_DIM * 2);          //  8.4 MB
  unsigned short* wqkvT    = (unsigned short*)take((size_t)E_NUM * N3 * D_DIM * 2);     // 50.3 MB
  unsigned short* wpT      = (unsigned short*)take((size_t)D_DIM * D_DIM * 2);          //  2.1 MB
  unsigned short* qkvslot  = (unsigned short*)take((size_t)B_TOK * 2 * N3 * 2);         // 50.3 MB
  unsigned short* attno    = (unsigned short*)take((size_t)B_TOK * D_DIM * 2);          //  8.4 MB
  int*   eoff        = (int*)take(16 * 4);
  int*   tok_expert  = (int*)take((size_t)B_TOK * 2 * 4);
  float* tok_weight  = (float*)take((size_t)B_TOK * 2 * 4);
  int*   tok_slot    = (int*)take((size_t)B_TOK * 2 * 4);
  int*   slot_token  = (int*)take((size_t)B_TOK * 2 * 4);
  float* slot_weight = (float*)take((size_t)B_TOK * 2 * 4);

  if (ws_size < off_b) return;  // ~128.5 MB required

  fused_prep_kernel<<<FUSED_B, 256, 0, stream>>>(x, y, Wg, bg, ebias, Wqkv, Wp,
                                                 xb, yb, wqkvT, wpT, tok_expert, tok_weight);
  route_kernel<<<1, 256, 0, stream>>>(tok_expert, tok_weight, eoff, slot_token,
                                      slot_weight, tok_slot);
  moe_gemm_kernel<<<MOE_NWG, 256, 0, stream>>>(yb, xb, wqkvT, qkvslot,
                                               slot_token, slot_weight, eoff);
  attn_kernel<<<B_TOK / 4, 256, 0, stream>>>(qkvslot, tok_slot, attno);
  final_gemm_kernel<<<dim3(8, 64), 256, 0, stream>>>(attno, wpT, bp, out);
}